// Round 7
// baseline (1503.330 us; speedup 1.0000x reference)
//
#include <hip/hip_runtime.h>
#include <hip/hip_bf16.h>
#include <math.h>

typedef unsigned short u16;
typedef unsigned int   u32;
typedef __bf16 bf16x8 __attribute__((ext_vector_type(8)));
typedef u16    u16x8  __attribute__((ext_vector_type(8)));
typedef float  f32x4  __attribute__((ext_vector_type(4)));

#define B_  8
#define L_  4096
#define H_  256
#define P_  512
#define NC_ 32
#define CH_ 128

__device__ __forceinline__ float bf2f(u16 v) { return __uint_as_float(((u32)v) << 16); }
__device__ __forceinline__ u16 f2bf(float f) {
  u32 u = __float_as_uint(f);
  u32 r = u + 0x7FFFu + ((u >> 16) & 1u);
  return (u16)(r >> 16);
}

// ------------------------------------------------------------- fp32 -> bf16
__global__ __launch_bounds__(256) void k_f2b(const float* __restrict__ src,
                                             u16* __restrict__ dst, int n) {
  int i = blockIdx.x * 256 + threadIdx.x;
  if (i < n) dst[i] = f2bf(src[i]);
}

// ---------------------------------------------------------------- adaLN mods
__global__ __launch_bounds__(256) void k_mods(const float* __restrict__ cond,
                                              const float* __restrict__ wada,
                                              const float* __restrict__ bada,
                                              float* __restrict__ mods) {
  __shared__ float s[256];
  int b = blockIdx.y;
  int j = (blockIdx.x << 8) + threadIdx.x;
  float c = cond[b * 256 + threadIdx.x];
  s[threadIdx.x] = c / (1.0f + expf(-c));
  __syncthreads();
  float acc = bada[j];
  const float* wr = wada + (size_t)j * 256;
#pragma unroll 8
  for (int k = 0; k < 256; ++k) acc += s[k] * wr[k];
  mods[b * 3072 + j] = acc;
}

// ------------------------------------------------------------- transposes
// fp32 [B,H,L] (batch b0+z) -> bf16 [nb*L, H]
__global__ __launch_bounds__(256) void k_tin(const float* __restrict__ in, u16* __restrict__ out,
                                             int b0) {
  __shared__ u16 tile[64][65];
  int b = blockIdx.z, l0 = blockIdx.x << 6, h0 = blockIdx.y << 6;
  int tx = threadIdx.x, ty = threadIdx.y;
#pragma unroll
  for (int i = 0; i < 16; ++i) {
    int h = h0 + ty + i * 4;
    tile[ty + i * 4][tx] = f2bf(in[((size_t)(b0 + b) * 256 + h) * 4096 + l0 + tx]);
  }
  __syncthreads();
#pragma unroll
  for (int i = 0; i < 16; ++i) {
    int l = l0 + ty + i * 4;
    out[((size_t)b * 4096 + l) * 256 + h0 + tx] = tile[tx][ty + i * 4];
  }
}
// bf16 [nb*L, H] -> fp32 [B,H,L] slab (dst pre-offset to b0's slab)
__global__ __launch_bounds__(256) void k_tout(const u16* __restrict__ src, float* __restrict__ dst) {
  __shared__ u16 tile[64][65];
  int b = blockIdx.z, l0 = blockIdx.x << 6, h0 = blockIdx.y << 6;
  int tx = threadIdx.x, ty = threadIdx.y;
#pragma unroll
  for (int i = 0; i < 16; ++i) {
    int l = l0 + ty + i * 4;
    tile[ty + i * 4][tx] = src[((size_t)b * 4096 + l) * 256 + h0 + tx];
  }
  __syncthreads();
#pragma unroll
  for (int i = 0; i < 16; ++i) {
    int h = h0 + ty + i * 4;
    dst[((size_t)b * 256 + h) * 4096 + l0 + tx] = bf2f(tile[tx][ty + i * 4]);
  }
}

// ------------------------------------------------------------- LN + adaLN mod
__global__ __launch_bounds__(256) void k_lnmod(const u16* __restrict__ X, u16* __restrict__ U,
                                               const float* __restrict__ mods,
                                               int sh_off, int sc_off, int b0) {
  int t = blockIdx.x, tid = threadIdx.x;
  int b = b0 + (t >> 12);
  float x = bf2f(X[(size_t)t * 256 + tid]);
  float s1 = x, s2 = x * x;
#pragma unroll
  for (int off = 32; off; off >>= 1) { s1 += __shfl_xor(s1, off); s2 += __shfl_xor(s2, off); }
  __shared__ float red[8];
  int w = tid >> 6;
  if ((tid & 63) == 0) { red[w * 2] = s1; red[w * 2 + 1] = s2; }
  __syncthreads();
  s1 = red[0] + red[2] + red[4] + red[6];
  s2 = red[1] + red[3] + red[5] + red[7];
  float m = s1 * (1.0f / 256.0f);
  float v = fmaxf(s2 * (1.0f / 256.0f) - m * m, 0.0f);
  float r = rsqrtf(v + 1e-6f);
  float sc = mods[b * 3072 + sc_off + tid];
  float sh = mods[b * 3072 + sh_off + tid];
  U[(size_t)t * 256 + tid] = f2bf((x - m) * r * (1.0f + sc) + sh);
}

// ------------------------------------------------------------- S5 weight prep
__global__ __launch_bounds__(256) void k_wb(const float* __restrict__ Lre,
                                            const float* __restrict__ Lim,
                                            const float* __restrict__ lstep,
                                            const float* __restrict__ Bre,
                                            const float* __restrict__ Bim,
                                            u16* __restrict__ WB) {
  int p = blockIdx.x, h = threadIdx.x;
  float lre = Lre[p], lim = Lim[p];
  float dt = expf(lstep[p]);
  float er = expf(lre * dt), sn, cs;
  sincosf(lim * dt, &sn, &cs);
  float ar = er * cs - 1.0f, ai = er * sn;
  float den = lre * lre + lim * lim;
  float cr = (ar * lre + ai * lim) / den;
  float ci = (ai * lre - ar * lim) / den;
  float br = Bre[p * 256 + h], bi = Bim[p * 256 + h];
  WB[(size_t)(2 * p) * 256 + h]     = f2bf(cr * br - ci * bi);
  WB[(size_t)(2 * p + 1) * 256 + h] = f2bf(cr * bi + ci * br);
}

__global__ __launch_bounds__(256) void k_wc(const float* __restrict__ Cre,
                                            const float* __restrict__ Cim,
                                            u16* __restrict__ WC, int col0) {
  int idx = (blockIdx.x << 8) + threadIdx.x;
  int h = idx >> 10, c = idx & 1023;
  float v = (c < 512) ? 2.0f * Cre[h * 1024 + col0 + c]
                      : -2.0f * Cim[h * 1024 + col0 + (c - 512)];
  WC[idx] = f2bf(v);
}

// ------------------------------------------------------------- chunked scan
__device__ __forceinline__ float2 lbar_of(const float* Lre, const float* Lim, const float* lstep,
                                          int p, float mul) {
  float dt = expf(lstep[p]) * mul;
  float er = expf(Lre[p] * dt), sn, cs;
  sincosf(Lim[p] * dt, &sn, &cs);
  return make_float2(er * cs, er * sn);
}

__global__ __launch_bounds__(256) void k_scanA(const float* Lre, const float* Lim, const float* lstep,
                                               const u16* __restrict__ Bu,
                                               float2* __restrict__ carries, int dir) {
  int g = (blockIdx.x << 8) + threadIdx.x;
  int p = g & 511, chunk = (g >> 9) & 31, bl = g >> 14;
  float2 a = lbar_of(Lre, Lim, lstep, p, 1.0f);
  float xr = 0.f, xi = 0.f;
  int l = dir ? (4095 - chunk * CH_) : (chunk * CH_);
  int step = dir ? -1 : 1;
  const u32* bup = (const u32*)Bu + (((size_t)((bl << 12) + l)) << 9) + p;
  long pstep = (long)step << 9;
#pragma unroll 8
  for (int j = 0; j < CH_; ++j) {
    u32 w = *bup;
    float br = bf2f((u16)(w & 0xFFFF)), bi = bf2f((u16)(w >> 16));
    float nr = a.x * xr - a.y * xi + br;
    float ni = a.x * xi + a.y * xr + bi;
    xr = nr; xi = ni;
    bup += pstep;
  }
  carries[g] = make_float2(xr, xi);
}

__global__ __launch_bounds__(256) void k_scanB(const float* Lre, const float* Lim, const float* lstep,
                                               const float2* __restrict__ carries,
                                               float2* __restrict__ carryin) {
  int g = (blockIdx.x << 8) + threadIdx.x;
  int p = g & 511, bl = g >> 9;
  float2 an = lbar_of(Lre, Lim, lstep, p, (float)CH_);
  float xr = 0.f, xi = 0.f;
  size_t base = (size_t)bl * 16384 + p;
  for (int c = 0; c < NC_; ++c) {
    size_t idx = base + (size_t)c * 512;
    carryin[idx] = make_float2(xr, xi);
    float2 E = carries[idx];
    float nr = an.x * xr - an.y * xi + E.x;
    float ni = an.x * xi + an.y * xr + E.y;
    xr = nr; xi = ni;
  }
}

__global__ __launch_bounds__(256) void k_scanC(const float* Lre, const float* Lim, const float* lstep,
                                               const u16* __restrict__ Bu,
                                               const float2* __restrict__ carryin,
                                               u16* __restrict__ xsh, int dir) {
  int g = (blockIdx.x << 8) + threadIdx.x;
  int p = g & 511, chunk = (g >> 9) & 31, bl = g >> 14;
  float2 a = lbar_of(Lre, Lim, lstep, p, 1.0f);
  float2 c0 = carryin[g];
  float xr = c0.x, xi = c0.y;
  int l = dir ? (4095 - chunk * CH_) : (chunk * CH_);
  int step = dir ? -1 : 1;
  const u32* bup = (const u32*)Bu + (((size_t)((bl << 12) + l)) << 9) + p;
  long pstep = (long)step << 9;
  u16* op = xsh + (((size_t)((bl << 12) + l)) << 10) + p;
  long rstep = (long)step << 10;
#pragma unroll 4
  for (int j = 0; j < CH_; ++j) {
    u32 w = *bup;
    float br = bf2f((u16)(w & 0xFFFF)), bi = bf2f((u16)(w >> 16));
    float nr = a.x * xr - a.y * xi + br;
    float ni = a.x * xi + a.y * xr + bi;
    xr = nr; xi = ni;
    op[0]   = f2bf(xr);
    op[512] = f2bf(xi);
    bup += pstep;
    op  += rstep;
  }
}

// ------------------------------------------------------------- MFMA GEMM (BT)
// MODE 0: bf16 store              MODE 1: gelu(acc+bias)
// MODE 2: acc+bias                MODE 3: acc+bias+add
// MODE 4: acc+bias+res            MODE 5: res + g*(acc+bias)
// MODE 6: c1=g*(acc+facc+D*uin); out=c1; out2(opt)=res+c1
// MODE 7: facc = acc (fp32)
template <int MODE>
__global__ __launch_bounds__(256) void gemm_bt(const u16* __restrict__ A, const u16* __restrict__ W,
                                               u16* __restrict__ out, int M, int N, int K,
                                               const float* __restrict__ bias,
                                               const float* __restrict__ gmods, int g_off, int b0,
                                               const u16* __restrict__ res, const u16* __restrict__ add,
                                               const u16* __restrict__ uin, const float* __restrict__ Dv,
                                               float* __restrict__ facc, u16* __restrict__ out2) {
  __shared__ __align__(16) u16 sA[128 * 64];
  __shared__ __align__(16) u16 sB[128 * 64];
  const int tid = threadIdx.x;
  const int wave = tid >> 6, lane = tid & 63;
  const int m0 = blockIdx.y << 7, n0 = blockIdx.x << 7;
  const int wm = (wave >> 1) << 6, wn = (wave & 1) << 6;
  const int lr = lane & 15;
  const int lk = (lane >> 4) << 3;
  const int srow = tid >> 3;
  const int scol = (tid & 7) << 3;

  f32x4 acc[4][4];
#pragma unroll
  for (int i = 0; i < 4; ++i)
#pragma unroll
    for (int j = 0; j < 4; ++j) acc[i][j] = (f32x4){0.f, 0.f, 0.f, 0.f};

  const u16* Ab = A + (size_t)(m0 + srow) * K + scol;
  const u16* Wb = W + (size_t)(n0 + srow) * K + scol;
  u16* lA = &sA[srow * 64 + scol];
  u16* lB = &sB[srow * 64 + scol];

  for (int k0 = 0; k0 < K; k0 += 64) {
    u16x8 ra[4], rb[4];
#pragma unroll
    for (int i = 0; i < 4; ++i) {
      ra[i] = *(const u16x8*)(Ab + (size_t)(i * 32) * K + k0);
      rb[i] = *(const u16x8*)(Wb + (size_t)(i * 32) * K + k0);
    }
    __syncthreads();
#pragma unroll
    for (int i = 0; i < 4; ++i) {
      *(u16x8*)(lA + i * 32 * 64) = ra[i];
      *(u16x8*)(lB + i * 32 * 64) = rb[i];
    }
    __syncthreads();
#pragma unroll
    for (int kk = 0; kk < 64; kk += 32) {
      bf16x8 af[4], bfr[4];
#pragma unroll
      for (int i = 0; i < 4; ++i) af[i] = *(const bf16x8*)&sA[(wm + i * 16 + lr) * 64 + kk + lk];
#pragma unroll
      for (int j = 0; j < 4; ++j) bfr[j] = *(const bf16x8*)&sB[(wn + j * 16 + lr) * 64 + kk + lk];
#pragma unroll
      for (int i = 0; i < 4; ++i)
#pragma unroll
        for (int j = 0; j < 4; ++j)
          acc[i][j] = __builtin_amdgcn_mfma_f32_16x16x32_bf16(af[i], bfr[j], acc[i][j], 0, 0, 0);
    }
  }

  const int lq = lane >> 4;
#pragma unroll
  for (int i = 0; i < 4; ++i)
#pragma unroll
    for (int j = 0; j < 4; ++j)
#pragma unroll
      for (int r = 0; r < 4; ++r) {
        int m = m0 + wm + i * 16 + lq * 4 + r;
        int n = n0 + wn + j * 16 + lr;
        float v = acc[i][j][r];
        size_t o = (size_t)m * N + n;
        if (MODE == 0) {
          out[o] = f2bf(v);
        } else if (MODE == 1) {
          float z = v + bias[n];
          out[o] = f2bf(0.5f * z * (1.0f + erff(z * 0.70710678118f)));
        } else if (MODE == 2) {
          out[o] = f2bf(v + bias[n]);
        } else if (MODE == 3) {
          out[o] = f2bf(v + bias[n] + bf2f(add[o]));
        } else if (MODE == 4) {
          out[o] = f2bf(v + bias[n] + bf2f(res[o]));
        } else if (MODE == 5) {
          int bb = b0 + (m >> 12);
          float g = gmods[bb * 3072 + g_off + n];
          out[o] = f2bf(bf2f(res[o]) + g * (v + bias[n]));
        } else if (MODE == 6) {
          int bb = b0 + (m >> 12);
          float g = gmods[bb * 3072 + g_off + n];
          float c1 = g * (v + facc[o] + Dv[n] * bf2f(uin[o]));
          out[o] = f2bf(c1);
          if (out2) out2[o] = f2bf(bf2f(res[o]) + c1);
        } else {
          facc[o] = v;
        }
      }
}

// ---------------------------------------------------------------- launcher
extern "C" void kernel_launch(void* const* d_in, const int* in_sizes, int n_in,
                              void* d_out, int out_size, void* d_ws, size_t ws_size,
                              hipStream_t stream) {
  (void)in_sizes; (void)n_in; (void)out_size;
  float* outp = (float*)d_out;   // fp32 output (reference returns float32)
#define F(i) ((const float*)d_in[i])

  char* ws = (char*)d_ws;
  float*  mods    = (float*)(ws + 0x000000);
  u16*    WBp     = (u16*)(ws + 0x020000);
  u16*    WBt     = (u16*)(ws + 0x0A0000);
  u16*    WCpf    = (u16*)(ws + 0x120000);
  u16*    WCpb    = (u16*)(ws + 0x1A0000);
  u16*    WCtf    = (u16*)(ws + 0x220000);
  u16*    WCtb    = (u16*)(ws + 0x2A0000);
  float2* carries = (float2*)(ws + 0x320000);
  float2* carryin = (float2*)(ws + 0x420000);
  u16*    wcv     = (u16*)(ws + 0x520000);   // 10 bf16 weight copies, 5 MiB

  const int widx[10] = {21, 23, 25, 27, 29, 31, 33, 35, 37, 39};
  const u16* WV[41];
  for (int i = 0; i < 10; ++i) {
    k_f2b<<<1024, 256, 0, stream>>>(F(widx[i]), wcv + (size_t)i * 262144, 262144);
    WV[widx[i]] = wcv + (size_t)i * 262144;
  }

  int nb = 1;
  for (int cand = 8; cand >= 1; cand >>= 1) {
    size_t need = (size_t)0x1000000 + (size_t)cand * 4096 * 9216;
    if (need <= ws_size) { nb = cand; break; }
  }
  const int R = nb * 4096;
  char* big = ws + 0x1000000;
  size_t sb = (size_t)R * 512;
  u16* Pt   = (u16*)(big);
  u16* Tt   = (u16*)(big + sb);
  u16* u_   = (u16*)(big + 2 * sb);
  u16* pcnd = (u16*)(big + 3 * sb);
  u16* p1   = (u16*)(big + 4 * sb);
  u16* tcb  = (u16*)(big + 5 * sb);
  u16* tmp1 = (u16*)(big + 6 * sb);
  u16* tmp2 = (u16*)(big + 7 * sb);
  u16* Bu   = (u16*)(big + 8 * sb);
  u16* xsh  = (u16*)(big + 12 * sb);
  float* fa = (float*)(big + 16 * sb);

  k_mods<<<dim3(12, 8), 256, 0, stream>>>(F(2), F(3), F(4), mods);
  k_wb<<<512, 256, 0, stream>>>(F(5), F(6), F(12), F(7), F(8), WBp);
  k_wb<<<512, 256, 0, stream>>>(F(13), F(14), F(20), F(15), F(16), WBt);
  k_wc<<<1024, 256, 0, stream>>>(F(9), F(10), WCpf, 0);
  k_wc<<<1024, 256, 0, stream>>>(F(9), F(10), WCpb, 512);
  k_wc<<<1024, 256, 0, stream>>>(F(17), F(18), WCtf, 0);
  k_wc<<<1024, 256, 0, stream>>>(F(17), F(18), WCtb, 512);

  for (int b0 = 0; b0 < 8; b0 += nb) {
#define GEMM(MODE, Aa, Ww, Oo, Nn, Kk, biasp, goff, resp, addp, uinp, Dp, fcp, o2)                 \
  gemm_bt<MODE><<<dim3((Nn) / 128, R / 128), 256, 0, stream>>>(                                    \
      (const u16*)(Aa), (const u16*)(Ww), (u16*)(Oo), R, (Nn), (Kk), (const float*)(biasp), mods,  \
      (goff), b0, (const u16*)(resp), (const u16*)(addp), (const u16*)(uinp), (const float*)(Dp),  \
      (float*)(fcp), (u16*)(o2))
#define SCANS(Lr, Li, Ls, dir)                                                                     \
  do {                                                                                             \
    k_scanA<<<nb * 64, 256, 0, stream>>>(Lr, Li, Ls, Bu, carries, dir);                            \
    k_scanB<<<nb * 2, 256, 0, stream>>>(Lr, Li, Ls, carries, carryin);                             \
    k_scanC<<<nb * 64, 256, 0, stream>>>(Lr, Li, Ls, Bu, carryin, xsh, dir);                       \
  } while (0)

    k_tin<<<dim3(64, 4, nb), dim3(64, 4), 0, stream>>>(F(0), Pt, b0);
    k_tin<<<dim3(64, 4, nb), dim3(64, 4), 0, stream>>>(F(1), Tt, b0);

    // ---- ppg S5
    k_lnmod<<<R, 256, 0, stream>>>(Pt, u_, mods, 0 * 256, 1 * 256, b0);
    GEMM(0, u_, WBp, Bu, 1024, 256, nullptr, 0, nullptr, nullptr, nullptr, nullptr, nullptr, nullptr);
    SCANS(F(5), F(6), F(12), 0);
    GEMM(7, xsh, WCpf, nullptr, 256, 1024, nullptr, 0, nullptr, nullptr, nullptr, nullptr, fa, nullptr);
    SCANS(F(5), F(6), F(12), 1);
    GEMM(6, xsh, WCpb, pcnd, 256, 1024, nullptr, 2 * 256, Pt, nullptr, u_, F(11), fa, p1);

    // ---- p-branch MLP -> output 0 (fp32)
    k_lnmod<<<R, 256, 0, stream>>>(p1, tmp1, mods, 3 * 256, 4 * 256, b0);
    GEMM(1, tmp1, WV[25], Bu, 1024, 256, F(26), 0, nullptr, nullptr, nullptr, nullptr, nullptr, nullptr);
    GEMM(5, Bu, WV[27], tmp2, 256, 1024, F(28), 5 * 256, Pt, nullptr, nullptr, nullptr, nullptr, nullptr);
    k_tout<<<dim3(64, 4, nb), dim3(64, 4), 0, stream>>>(tmp2, outp + (size_t)b0 * 1048576);

    // ---- tgt S5
    k_lnmod<<<R, 256, 0, stream>>>(Tt, u_, mods, 6 * 256, 7 * 256, b0);
    GEMM(0, u_, WBt, Bu, 1024, 256, nullptr, 0, nullptr, nullptr, nullptr, nullptr, nullptr, nullptr);
    SCANS(F(13), F(14), F(20), 0);
    GEMM(7, xsh, WCtf, nullptr, 256, 1024, nullptr, 0, nullptr, nullptr, nullptr, nullptr, fa, nullptr);
    SCANS(F(13), F(14), F(20), 1);
    GEMM(6, xsh, WCtb, tcb, 256, 1024, nullptr, 8 * 256, nullptr, nullptr, u_, F(19), fa, nullptr);

    // ---- tc chain + dx -> output 1 (fp32)
    GEMM(1, pcnd, WV[21], Bu, 1024, 256, F(22), 0, nullptr, nullptr, nullptr, nullptr, nullptr, nullptr);
    GEMM(2, Bu, WV[23], tmp1, 256, 1024, F(24), 0, nullptr, nullptr, nullptr, nullptr, nullptr, nullptr);
    GEMM(1, tcb, WV[29], Bu, 1024, 256, F(30), 0, nullptr, nullptr, nullptr, nullptr, nullptr, nullptr);
    GEMM(3, Bu, WV[31], tmp2, 256, 1024, F(32), 0, nullptr, tmp1, nullptr, nullptr, nullptr, nullptr);
    GEMM(1, tmp2, WV[33], Bu, 1024, 256, F(34), 0, nullptr, nullptr, nullptr, nullptr, nullptr, nullptr);
    GEMM(4, Bu, WV[35], tcb, 256, 1024, F(36), 0, Tt, nullptr, nullptr, nullptr, nullptr, nullptr);
    k_lnmod<<<R, 256, 0, stream>>>(tcb, tmp1, mods, 9 * 256, 10 * 256, b0);
    GEMM(1, tmp1, WV[37], Bu, 1024, 256, F(38), 0, nullptr, nullptr, nullptr, nullptr, nullptr, nullptr);
    GEMM(5, Bu, WV[39], tmp2, 256, 1024, F(40), 11 * 256, Tt, nullptr, nullptr, nullptr, nullptr, nullptr);
    k_tout<<<dim3(64, 4, nb), dim3(64, 4), 0, stream>>>(tmp2, outp + 8388608 + (size_t)b0 * 1048576);

#undef GEMM
#undef SCANS
  }
#undef F
}